// Round 15
// baseline (60.170 us; speedup 1.0000x reference)
//
#include <hip/hip_runtime.h>
#include <hip/hip_bf16.h>

// QLoRA SwiGLU MLP, B=16 tokens, d=4096, h=11008, r=2.
// tile(wq,(1,4)) => x @ W^T == fold4(x) @ wq^T  (skinny GEMM, K = in/4).
// R15: contiguous-window staging. Evidence: every gateup variant with
// concurrent 4KB-strided (power-of-2) reads = 2 TB/s; k_down (11008B row
// stride, non-pow2) = ~6 TB/s; linear fill = 6.7 TB/s. Theory: 4KB-stride
// concurrency aliases HBM channels / cache sets. Fix: a 16-row x K tile is
// CONTIGUOUS 64KB; stage it whole (wave w = rows 4w..4w+3, 16 linear 1KB
// DMAs), vmcnt(0)+raw s_barrier, MFMA from LDS, rotate w1->w3 in one buffer.
// 72KB LDS -> 2 blocks/CU; cross-block overlap hides stage/compute phases.
// down/prep1/epilogues identical to R13/R14 (passing).

#define NB     16
#define DMODEL 4096
#define HID    11008
#define DQ     1024   // DMODEL/4
#define HQ     2752   // HID/4

// workspace layout (float offsets)
#define XSB_OFF 0         // xs bf16 [16][1024] = 8192 floats
#define T1_OFF  8192      // [16][2] f32
#define T3_OFF  8224
#define HF_OFF  8256      // hfold f32 [16][2752] = 44032 floats
#define T2_OFF  52288     // [16][2] f32  (zeroed with hfold by prep1)

typedef __attribute__((ext_vector_type(8))) short bf16x8;
typedef __attribute__((ext_vector_type(4))) float f32x4;

__device__ __forceinline__ unsigned short f2bfh(float f) {
  __hip_bfloat16 h = __float2bfloat16(f);   // v_cvt, RNE
  return __builtin_bit_cast(unsigned short, h);
}
__device__ __forceinline__ unsigned pack2(float lo, float hi) {
  return (unsigned)f2bfh(lo) | ((unsigned)f2bfh(hi) << 16);
}
__device__ __forceinline__ bf16x8 cvt8(const float4 a, const float4 b) {
  uint4 u = make_uint4(pack2(a.x, a.y), pack2(a.z, a.w),
                       pack2(b.x, b.y), pack2(b.z, b.w));
  return __builtin_bit_cast(bf16x8, u);
}
__device__ __forceinline__ void gload_lds16(const float* g, float* l) {
  __builtin_amdgcn_global_load_lds(
      (const __attribute__((address_space(1))) void*)g,
      (__attribute__((address_space(3))) void*)l, 16, 0, 0);
}

#define SB       __builtin_amdgcn_sched_barrier(0)
#define BAR      __builtin_amdgcn_s_barrier()
#define WAITV(N) asm volatile("s_waitcnt vmcnt(" #N ")" ::: "memory")
#define WAITL    asm volatile("s_waitcnt lgkmcnt(0)" ::: "memory")

// ---------------------------------------------------------------------------
// prep1: 64 blocks. All blocks zero hfold/T2/out; blocks 0-15 also compute
// xs[b] = fold4(x[b]) (bf16) and t1,t3 LoRA-A dots.
__global__ __launch_bounds__(256) void k_prep1(const float* __restrict__ x,
                                               const float* __restrict__ a1,
                                               const float* __restrict__ a3,
                                               float* __restrict__ ws,
                                               float* __restrict__ out) {
  const int t = threadIdx.x;
  const int gid = blockIdx.x * 256 + t;        // 0..16383
  const float4 z4 = make_float4(0.f, 0.f, 0.f, 0.f);
  if (gid < 11016) ((float4*)(ws + HF_OFF))[gid] = z4;   // hfold + T2
  ((float4*)out)[gid] = z4;                               // out: 16384 f4
  if (blockIdx.x >= 16) return;

  const int b = blockIdx.x;
  const float4* x4  = (const float4*)(x) + b * (DMODEL / 4);
  const float4* a14 = (const float4*)a1;
  const float4* a34 = (const float4*)a3;
  float4 xs = z4;
  float s10 = 0.f, s11 = 0.f, s30 = 0.f, s31 = 0.f;
#pragma unroll
  for (int k = 0; k < 4; ++k) {
    float4 xv  = x4[k * 256 + t];
    xs.x += xv.x; xs.y += xv.y; xs.z += xv.z; xs.w += xv.w;
    float4 a10 = a14[k * 256 + t];
    float4 a11 = a14[1024 + k * 256 + t];
    float4 a30 = a34[k * 256 + t];
    float4 a31 = a34[1024 + k * 256 + t];
    s10 += xv.x * a10.x + xv.y * a10.y + xv.z * a10.z + xv.w * a10.w;
    s11 += xv.x * a11.x + xv.y * a11.y + xv.z * a11.z + xv.w * a11.w;
    s30 += xv.x * a30.x + xv.y * a30.y + xv.z * a30.z + xv.w * a30.w;
    s31 += xv.x * a31.x + xv.y * a31.y + xv.z * a31.z + xv.w * a31.w;
  }
  ((uint2*)(ws + XSB_OFF))[b * 256 + t] =
      make_uint2(pack2(xs.x, xs.y), pack2(xs.z, xs.w));

  __shared__ float4 rb[256];
  rb[t] = make_float4(s10, s11, s30, s31);
  __syncthreads();
  for (int s = 128; s > 0; s >>= 1) {
    if (t < s) {
      rb[t].x += rb[t + s].x; rb[t].y += rb[t + s].y;
      rb[t].z += rb[t + s].z; rb[t].w += rb[t + s].w;
    }
    __syncthreads();
  }
  if (t == 0) {
    ws[T1_OFF + b * 2]     = rb[0].x;
    ws[T1_OFF + b * 2 + 1] = rb[0].y;
    ws[T3_OFF + b * 2]     = rb[0].z;
    ws[T3_OFF + b * 2 + 1] = rb[0].w;
  }
}

// ---------------------------------------------------------------------------
// gateup: 688 blocks x 256 thr (4 waves). Block = 16 rows; the 16xK tile of
// each matrix is a CONTIGUOUS 64KB span. Stage whole tile (wave w: DMA
// instr q = w*16+i covers global bytes [q KB,(q+1) KB) of the span; dest
// LDS slot q*64+lane -> linear). vmcnt(0)+s_barrier, each wave MFMAs its
// K-quarter from LDS. Rotate w1 -> w3 in the same buffer.
#define GU_STAGE(MAT) do {                                                  \
    _Pragma("unroll")                                                       \
    for (int _i = 0; _i < 16; ++_i) {                                       \
      const int _q = w * 16 + _i;                                           \
      const float* _src = (MAT) + (size_t)(row0 + (_q >> 2)) * DQ +         \
                          (((_q & 3) << 6) + l) * 4;                        \
      gload_lds16(_src, (float*)(tile) + _q * 256);                         \
    }                                                                       \
  } while (0)

#define GU_COMP(ACC) do {                                                   \
    _Pragma("unroll")                                                       \
    for (int _q = 0; _q < 8; ++_q) {                                        \
      const float* _pa = (const float*)tile + n * 1024 + w * 256 +          \
                         _q * 32 + g * 8;                                   \
      const float4 _a0 = *(const float4*)_pa;                               \
      const float4 _a1 = *(const float4*)(_pa + 4);                         \
      ACC = __builtin_amdgcn_mfma_f32_16x16x32_bf16(cvt8(_a0, _a1),         \
                bb[_q], ACC, 0, 0, 0);                                      \
    }                                                                       \
  } while (0)

__global__ __launch_bounds__(256) void k_gateup(const float* __restrict__ w1q,
                                                const float* __restrict__ w3q,
                                                const float* __restrict__ b1,
                                                const float* __restrict__ b3,
                                                const float* __restrict__ a2,
                                                float* __restrict__ ws) {
  __shared__ float4 tile[4096];   // 64 KB: one 16-row x K matrix tile
  __shared__ float red[2048];     // 8 KB cross-wave reduce
  const int t = threadIdx.x, w = t >> 6, l = t & 63;
  const int row0 = blockIdx.x * 16;
  const int n = l & 15, g = l >> 4;
  const unsigned short* xsb = (const unsigned short*)(ws + XSB_OFF);

  // B-fragments (xs, L2-hot): wave w's K-quarter, shared by w1 and w3.
  bf16x8 bb[8];
#pragma unroll
  for (int q = 0; q < 8; ++q)
    bb[q] = *(const bf16x8*)(xsb + n * DQ + w * 256 + q * 32 + g * 8);

  f32x4 acc1 = {0.f, 0.f, 0.f, 0.f}, acc3 = {0.f, 0.f, 0.f, 0.f};

  GU_STAGE(w1q);
  WAITV(0); SB; BAR;              // w1 tile staged (all waves)
  GU_COMP(acc1);
  WAITL; SB; BAR;                 // all waves done reading w1
  GU_STAGE(w3q);
  WAITV(0); SB; BAR;              // w3 tile staged
  GU_COMP(acc3);

#pragma unroll
  for (int r = 0; r < 4; ++r) {
    red[(w * 8 + r) * 64 + l]     = acc1[r];
    red[(w * 8 + r + 4) * 64 + l] = acc3[r];
  }
  __syncthreads();
  if (w == 0) {
    const float t10 = ws[T1_OFF + 2 * n], t11 = ws[T1_OFF + 2 * n + 1];
    const float t30 = ws[T3_OFF + 2 * n], t31 = ws[T3_OFF + 2 * n + 1];
    const int m4 = g * 4;
    float s0 = 0.f, s1 = 0.f;     // t2 partials for token n
#pragma unroll
    for (int r = 0; r < 4; ++r) {
      float g0 = 0.f, u0 = 0.f;
#pragma unroll
      for (int ww = 0; ww < 4; ++ww) {
        g0 += red[(ww * 8 + r) * 64 + l];
        u0 += red[(ww * 8 + r + 4) * 64 + l];
      }
      const int oo = row0 + m4 + r;
      const float gg = g0 + 0.5f * (t10 * b1[2 * oo] + t11 * b1[2 * oo + 1]);
      const float uu = u0 + 0.5f * (t30 * b3[2 * oo] + t31 * b3[2 * oo + 1]);
      const float v = (gg / (1.f + __expf(-gg))) * uu;
      atomicAdd(&ws[HF_OFF + n * HQ + (oo % HQ)], v);
      s0 += v * a2[oo];
      s1 += v * a2[HID + oo];
    }
    s0 += __shfl_xor(s0, 16);  s0 += __shfl_xor(s0, 32);
    s1 += __shfl_xor(s1, 16);  s1 += __shfl_xor(s1, 32);
    if (l < 16) {
      atomicAdd(&ws[T2_OFF + 2 * n], s0);
      atomicAdd(&ws[T2_OFF + 2 * n + 1], s1);
    }
  }
}

// ---------------------------------------------------------------------------
// down: 512 blocks x 256 thr (4 waves), identical to R13/R14 (passing,
// ~6 TB/s — its 11008B row stride is non-pow2, no channel aliasing).
#define DN_ISSUE(CB, BUF) do {                                              \
    _Pragma("unroll")                                                       \
    for (int _i = 0; _i < 8; ++_i) {                                        \
      const float* _src = w2q + (size_t)(row0 + n) * HQ +                   \
                          (hbase + (CB)) * 32 + (_i * 4 + g) * 4;           \
      gload_lds16(_src, (float*)(ldsv + w4 + (BUF) * 512 + _i * 64));       \
    }                                                                       \
  } while (0)

#define DN_HF(CB, H) do {                                                   \
    _Pragma("unroll")                                                       \
    for (int _k = 0; _k < 4; ++_k) {                                        \
      const float* _p = hf + (size_t)n * HQ + (hbase + (CB) + _k) * 32 + kb;\
      H[2 * _k]     = *(const float4*)_p;                                   \
      H[2 * _k + 1] = *(const float4*)(_p + 4);                             \
    }                                                                       \
  } while (0)

#define DN_COMP(CB, BUF, H, LO, HI) do {                                    \
    _Pragma("unroll")                                                       \
    for (int _kk = 0; _kk < 4; ++_kk) {                                     \
      if ((CB) + _kk >= (LO) && (CB) + _kk < (HI)) {                        \
        const int _u0 = _kk * 8 + 2 * g;                                    \
        const float4 _a  = *(const float4*)(ldsv + w4 + (BUF) * 512 +       \
                                            _u0 * 16 + n);                  \
        const float4 _b2 = *(const float4*)(ldsv + w4 + (BUF) * 512 +       \
                                            (_u0 + 1) * 16 + n);            \
        acc = __builtin_amdgcn_mfma_f32_16x16x32_bf16(cvt8(_a, _b2),        \
                  cvt8(H[2 * _kk], H[2 * _kk + 1]), acc, 0, 0, 0);          \
      }                                                                     \
    }                                                                       \
  } while (0)

__global__ __launch_bounds__(256) void k_down(const float* __restrict__ w2q,
                                              const float* __restrict__ b2,
                                              const float* __restrict__ ws,
                                              float* __restrict__ out) {
  __shared__ float4 ldsv[4096];
  __shared__ float red[1024];
  const int t = threadIdx.x, w = t >> 6, l = t & 63;
  const int tile = blockIdx.x >> 1, half = blockIdx.x & 1;
  const int row0 = tile * 16;
  const int hbase = half * 43;
  const int n = l & 15, g = l >> 4, kb = g * 8;
  const int w4 = w * 1024;
  const float* hf = ws + HF_OFF;

  const int wstart = (w == 0) ? 0 : (w == 1) ? 12 : (w == 2) ? 23 : 33;
  const int vlen   = (w == 0) ? 12 : (w == 1) ? 11 : 10;
  const int cb0 = wstart, cb1 = wstart + 4;
  const int cb2t = wstart + 8;
  const int cb2 = (cb2t > 39) ? 39 : cb2t;     // clamp staging in-bounds
  const int hi2 = wstart + vlen;

  f32x4 acc = {0.f, 0.f, 0.f, 0.f};
  float4 h0[8], h1[8], h2[8];

  DN_ISSUE(cb0, 0); SB;
  DN_HF(cb0, h0);   SB;
  DN_ISSUE(cb1, 1); SB;
  DN_HF(cb1, h1);   SB;
  WAITV(16); SB;                  // DMA0 + hf0 retired
  DN_COMP(cb0, 0, h0, 0, 9999);
  WAITL; SB;
  DN_ISSUE(cb2, 0); SB;
  DN_HF(cb2, h2);   SB;
  WAITV(16); SB;                  // DMA1 + hf1 retired
  DN_COMP(cb1, 1, h1, 0, 9999);
  WAITV(0); SB;
  DN_COMP(cb2, 0, h2, cb2t, hi2);

#pragma unroll
  for (int r = 0; r < 4; ++r) red[(w * 4 + r) * 64 + l] = acc[r];
  __syncthreads();
  if (w == 0) {
    const float t20 = ws[T2_OFF + 2 * n], t21 = ws[T2_OFF + 2 * n + 1];
    const int m4 = g * 4;
#pragma unroll
    for (int r = 0; r < 4; ++r) {
      float v = red[r * 64 + l] + red[(4 + r) * 64 + l] +
                red[(8 + r) * 64 + l] + red[(12 + r) * 64 + l];
      const int oo = row0 + m4 + r;
      if (half == 0)
        v += 0.5f * (t20 * b2[2 * oo] + t21 * b2[2 * oo + 1]);
      atomicAdd(&out[n * DMODEL + oo], v);
    }
  }
}

// ---------------------------------------------------------------------------
extern "C" void kernel_launch(void* const* d_in, const int* in_sizes, int n_in,
                              void* d_out, int out_size, void* d_ws, size_t ws_size,
                              hipStream_t stream) {
  const float* x   = (const float*)d_in[0];
  const float* w1q = (const float*)d_in[1];
  const float* a1  = (const float*)d_in[2];
  const float* b1  = (const float*)d_in[3];
  const float* w3q = (const float*)d_in[4];
  const float* a3  = (const float*)d_in[5];
  const float* b3  = (const float*)d_in[6];
  const float* w2q = (const float*)d_in[7];
  const float* a2  = (const float*)d_in[8];
  const float* b2  = (const float*)d_in[9];
  float* out = (float*)d_out;
  float* ws  = (float*)d_ws;

  k_prep1<<<64, 256, 0, stream>>>(x, a1, a3, ws, out);
  k_gateup<<<HID / 16, 256, 0, stream>>>(w1q, w3q, b1, b3, a2, ws);
  k_down<<<512, 256, 0, stream>>>(w2q, b2, ws, out);
}